// Round 8
// baseline (7477.931 us; speedup 1.0000x reference)
//
#include <hip/hip_runtime.h>
#include <stdint.h>

// LSTMModel: 4-layer LSTM (B=256,T=512,H=256,Din=28) + sigmoid proj (21)
// R7: recovery + consolidation. R4 skeleton (proven) with: per-WG sentinel
// slots (no atomicAdd chain), tid0 poll caching + hot spin, weights in
// registers (B-frags), single-batch staging, t=0 rec skip (no hbuf zeroing).
// All cross-WG traffic agent-scope via MALL (proven visible).

#define B 256
#define T 512
#define H 256
#define DIN 28
#define NWG 256
#define OUTD 21

typedef __attribute__((ext_vector_type(8))) __bf16 bf16x8;
typedef __attribute__((ext_vector_type(4))) float f32x4;
typedef __attribute__((ext_vector_type(4))) unsigned short u16x4;
typedef unsigned long long u64;

// ---- workspace layout (bytes) ----
#define WS_SENT  0ull                                   // 32 grp * 16 u32 = 2 KB
#define WS_HBUF  2048ull                                // [l][slot4][b][j] bf16: 2 MB
#define WS_XBF   (WS_HBUF + 4ull*4*B*H*2)               // x bf16 [b][t][32]: 8 MB
#define WS_WIH0  (WS_XBF + (u64)B*T*32*2)
#define WS_WIHR  (WS_WIH0 + 1024ull*32*2)
#define WS_WHHR  (WS_WIHR + 3ull*1024*256*2)
#define WS_BIAS  (WS_WHHR + 4ull*1024*256*2)
#define WS_ZERO  2048ull                                // memset: sentinels only

__device__ __forceinline__ unsigned short f2bf(float f) {
  unsigned u = __builtin_bit_cast(unsigned, f);
  u += 0x7fffu + ((u >> 16) & 1u);
  return (unsigned short)(u >> 16);
}
__device__ __forceinline__ float bf2f(unsigned short v) {
  return __builtin_bit_cast(float, (unsigned)v << 16);
}
__device__ __forceinline__ float sigf(float x) { return 1.f / (1.f + __expf(-x)); }
__device__ __forceinline__ float tanhfast(float x) {
  float e = __expf(2.f * x);
  return 1.f - 2.f / (e + 1.f);
}
__device__ __forceinline__ u64 ldq(const u64* p) {
  return __hip_atomic_load(p, __ATOMIC_RELAXED, __HIP_MEMORY_SCOPE_AGENT);
}
__device__ __forceinline__ void stq(void* p, u64 v) {
  __hip_atomic_store((u64*)p, v, __ATOMIC_RELAXED, __HIP_MEMORY_SCOPE_AGENT);
}
__device__ __forceinline__ void stw_agent(unsigned* p, unsigned v) {
  __hip_atomic_store(p, v, __ATOMIC_RELAXED, __HIP_MEMORY_SCOPE_AGENT);
}
__device__ __forceinline__ unsigned umin2(unsigned a, unsigned b) { return a < b ? a : b; }
__device__ __forceinline__ unsigned min16_agent(const unsigned* p) {
  unsigned m = 0xFFFFFFFFu;
  const u64* q = (const u64*)p;
#pragma unroll
  for (int i = 0; i < 8; ++i) {
    u64 v = ldq(q + i);
    m = umin2(m, umin2((unsigned)v, (unsigned)(v >> 32)));
  }
  return m;
}

// ---------------- prep kernels ----------------
__global__ void prep_x(const float* __restrict__ x, unsigned short* __restrict__ xbf) {
  int tot = B * T * 32;
  for (int idx = blockIdx.x * blockDim.x + threadIdx.x; idx < tot;
       idx += gridDim.x * blockDim.x) {
    int kk = idx & 31;
    int bt = idx >> 5;
    float v = (kk < DIN) ? x[(size_t)bt * DIN + kk] : 0.f;
    xbf[idx] = f2bf(v);
  }
}

__global__ void prep_w(const float* __restrict__ wih0, const float* __restrict__ wihrest,
                       const float* __restrict__ whh, const float* __restrict__ bih,
                       const float* __restrict__ bhh,
                       unsigned short* __restrict__ wih0r, unsigned short* __restrict__ wihr,
                       unsigned short* __restrict__ whhr, float* __restrict__ biasr) {
  const int R0 = 1024 * 32, R1 = 3 * 1024 * 256, R2 = 4 * 1024 * 256, R3 = 4 * 1024;
  int tot = R0 + R1 + R2 + R3;
  for (int idx = blockIdx.x * blockDim.x + threadIdx.x; idx < tot;
       idx += gridDim.x * blockDim.x) {
    if (idx < R0) {
      int k = idx & 31, np = idx >> 5, g = np & 3, j = np >> 2;
      wih0r[idx] = f2bf(k < DIN ? wih0[(size_t)(g * 256 + j) * DIN + k] : 0.f);
    } else if (idx < R0 + R1) {
      int i = idx - R0;
      int k = i & 255, r = i >> 8, np = r & 1023, l = r >> 10, g = np & 3, j = np >> 2;
      wihr[i] = f2bf(wihrest[((size_t)l * 1024 + g * 256 + j) * 256 + k]);
    } else if (idx < R0 + R1 + R2) {
      int i = idx - R0 - R1;
      int k = i & 255, r = i >> 8, np = r & 1023, l = r >> 10, g = np & 3, j = np >> 2;
      whhr[i] = f2bf(whh[((size_t)l * 1024 + g * 256 + j) * 256 + k]);
    } else {
      int i = idx - R0 - R1 - R2;
      int np = i & 1023, l = i >> 10, g = np & 3, j = np >> 2;
      biasr[i] = bih[l * 1024 + g * 256 + j] + bhh[l * 1024 + g * 256 + j];
    }
  }
}

// ---------------- main persistent kernel ----------------
__device__ __forceinline__ void mstep2(const unsigned char* Ap, int kb, int ar0, int ar1,
                                       bf16x8 b0, bf16x8 b1, f32x4& a00, f32x4& a01,
                                       f32x4& a10, f32x4& a11) {
  bf16x8 a0 = *(const bf16x8*)(Ap + ar0 * 1024 + (kb ^ ((ar0 & 15) << 4)));
  bf16x8 a1 = *(const bf16x8*)(Ap + ar1 * 1024 + (kb ^ ((ar1 & 15) << 4)));
  a00 = __builtin_amdgcn_mfma_f32_16x16x32_bf16(a0, b0, a00, 0, 0, 0);
  a01 = __builtin_amdgcn_mfma_f32_16x16x32_bf16(a0, b1, a01, 0, 0, 0);
  a10 = __builtin_amdgcn_mfma_f32_16x16x32_bf16(a1, b0, a10, 0, 0, 0);
  a11 = __builtin_amdgcn_mfma_f32_16x16x32_bf16(a1, b1, a11, 0, 0, 0);
}

__launch_bounds__(256, 1)
__global__ void lstm_main(const unsigned short* __restrict__ xbf,
                          const unsigned short* __restrict__ wih0r,
                          const unsigned short* __restrict__ wihr,
                          const unsigned short* __restrict__ whhr,
                          const float* __restrict__ biasr,
                          const float* __restrict__ Wout, const float* __restrict__ bout,
                          unsigned short* __restrict__ hbuf, unsigned* __restrict__ sent,
                          float* __restrict__ out) {
  __shared__ unsigned char Ap[64 * 1024];   // A panel: 64 b-rows x 1KB, XOR-swizzled
  __shared__ float gates[64 * 68];          // [n'rel][brel] exchange, stride 68

  const int tid = threadIdx.x;
  const int lane = tid & 63;
  const int w = tid >> 6;
  const int wb = w >> 1, wn = w & 1;
  const int bid = blockIdx.x;
  const int layer = (bid & 7) >> 1;
  const int wgl = ((bid >> 3) << 1) | (bid & 1);
  const int b0g = wgl >> 4;
  const int b0 = b0g * 64;
  const int ntile = wgl & 15;
  const int n0 = ntile * 64;
  const int j0 = ntile * 16;
  const int mygrp = layer * 4 + b0g;

  unsigned* sent_own = sent + mygrp * 16;
  const unsigned* sent_up = (layer > 0) ? sent + (mygrp - 4) * 16 : sent_own;
  const unsigned* sent_dn = (layer < 3) ? sent + (mygrp + 4) * 16 : sent_own;

  // ---- weights -> registers (B fragments), bias ----
  const int brow0 = wn * 32 + (lane & 15);
  const int brow1 = brow0 + 16;
  const int koff8 = (lane >> 4) * 8;     // short offset within 32-K chunk
  const int akoff2 = (lane >> 4) * 16;   // byte offset
  bf16x8 bA[16], bB[16];
  if (layer == 0) {
    bA[0] = *(const bf16x8*)(wih0r + (size_t)(n0 + brow0) * 32 + koff8);
    bB[0] = *(const bf16x8*)(wih0r + (size_t)(n0 + brow1) * 32 + koff8);
#pragma unroll
    for (int kk = 0; kk < 8; ++kk) {
      bA[1 + kk] = *(const bf16x8*)(whhr + (size_t)(n0 + brow0) * 256 + kk * 32 + koff8);
      bB[1 + kk] = *(const bf16x8*)(whhr + (size_t)(n0 + brow1) * 256 + kk * 32 + koff8);
    }
  } else {
#pragma unroll
    for (int kk = 0; kk < 8; ++kk) {
      bA[kk] = *(const bf16x8*)(wihr + ((size_t)(layer - 1) * 1024 + n0 + brow0) * 256 +
                                kk * 32 + koff8);
      bB[kk] = *(const bf16x8*)(wihr + ((size_t)(layer - 1) * 1024 + n0 + brow1) * 256 +
                                kk * 32 + koff8);
      bA[8 + kk] = *(const bf16x8*)(whhr + ((size_t)layer * 1024 + n0 + brow0) * 256 +
                                    kk * 32 + koff8);
      bB[8 + kk] = *(const bf16x8*)(whhr + ((size_t)layer * 1024 + n0 + brow1) * 256 +
                                    kk * 32 + koff8);
    }
  }
  const float bv0 = biasr[layer * 1024 + n0 + wn * 32 + (lane & 15)];
  const float bv1 = biasr[layer * 1024 + n0 + wn * 32 + 16 + (lane & 15)];

  const int arow0 = wb * 32 + (lane & 15);
  const int arow1 = arow0 + 16;
  const int strow = tid >> 2;                  // staging row 0..63
  const int stchunk = tid & 3;                 // 128B chunk
  const int srs = (strow & 15) << 4;           // row swizzle
  const int recoff = (layer == 0) ? 64 : 512;  // rec-K byte base within panel row

  f32x4 creg = {0.f, 0.f, 0.f, 0.f};
  unsigned cache_up = 0, cache_dn = 0;

  for (int t = 0; t < T; ++t) {
    // ---- gating: tid0 polls sentinel lines (cached for ff/bp edges) ----
    if (tid == 0) {
      int it = 0;
      if (t > 0) {
        while (min16_agent(sent_own) < (unsigned)t) {
          if (++it > 32) __builtin_amdgcn_s_sleep(1);
        }
      }
      if (layer > 0 && cache_up < (unsigned)(t + 1)) {
        while ((cache_up = min16_agent(sent_up)) < (unsigned)(t + 1)) {
          if (++it > 32) __builtin_amdgcn_s_sleep(1);
        }
      }
      if (layer < 3 && t >= 4 && cache_dn < (unsigned)(t - 3)) {
        while ((cache_dn = min16_agent(sent_dn)) < (unsigned)(t - 3)) {
          if (++it > 32) __builtin_amdgcn_s_sleep(1);
        }
      }
    }
    __syncthreads();
    asm volatile("" ::: "memory");

    // ---- stage: issue all panel loads in one batch (rec + prev) ----
    u64 rv[16], pv[16];
    uint4 xg;
    const unsigned short* hbR = hbuf + ((size_t)layer * 4 + ((t - 1) & 3)) * 65536;
    if (t > 0) {
      const u64* rp = (const u64*)(hbR + (size_t)(b0 + strow) * 256 + stchunk * 64);
#pragma unroll
      for (int i = 0; i < 16; ++i) rv[i] = ldq(rp + i);
    }
    if (layer == 0) {
      xg = *(const uint4*)(xbf + ((size_t)(b0 + strow) * T + t) * 32 + stchunk * 8);
    } else {
      const u64* pp = (const u64*)(hbuf + ((size_t)(layer - 1) * 4 + (t & 3)) * 65536 +
                                   (size_t)(b0 + strow) * 256 + stchunk * 64);
#pragma unroll
      for (int i = 0; i < 16; ++i) pv[i] = ldq(pp + i);
    }
    __builtin_amdgcn_sched_barrier(0);

    // ---- write panel to LDS (swizzled) ----
    {
      unsigned char* wbase = Ap + strow * 1024;
      if (t > 0) {
        int rb = recoff + stchunk * 128;
#pragma unroll
        for (int i = 0; i < 8; ++i) {
          uint4 v;
          ((u64*)&v)[0] = rv[2 * i];
          ((u64*)&v)[1] = rv[2 * i + 1];
          *(uint4*)(wbase + ((rb + i * 16) ^ srs)) = v;
        }
      }
      if (layer == 0) {
        *(uint4*)(wbase + ((stchunk * 16) ^ srs)) = xg;
      } else {
        int pb = stchunk * 128;
#pragma unroll
        for (int i = 0; i < 8; ++i) {
          uint4 v;
          ((u64*)&v)[0] = pv[2 * i];
          ((u64*)&v)[1] = pv[2 * i + 1];
          *(uint4*)(wbase + ((pb + i * 16) ^ srs)) = v;
        }
      }
    }
    __syncthreads();

    // ---- MFMAs (A from LDS, B from registers) ----
    f32x4 a00 = {bv0, bv0, bv0, bv0};
    f32x4 a01 = {bv1, bv1, bv1, bv1};
    f32x4 a10 = a00, a11 = a01;
    if (layer == 0) {
      mstep2(Ap, akoff2, arow0, arow1, bA[0], bB[0], a00, a01, a10, a11);
      if (t > 0) {
#pragma unroll
        for (int kk = 0; kk < 8; ++kk)
          mstep2(Ap, 64 + kk * 64 + akoff2, arow0, arow1, bA[1 + kk], bB[1 + kk],
                 a00, a01, a10, a11);
      }
    } else {
#pragma unroll
      for (int kk = 0; kk < 8; ++kk)
        mstep2(Ap, kk * 64 + akoff2, arow0, arow1, bA[kk], bB[kk], a00, a01, a10, a11);
      if (t > 0) {
#pragma unroll
        for (int kk = 0; kk < 8; ++kk)
          mstep2(Ap, 512 + kk * 64 + akoff2, arow0, arow1, bA[8 + kk], bB[8 + kk],
                 a00, a01, a10, a11);
      }
    }

    // ---- scatter acc frags to gates[n'rel][brel] ----
    {
      int c = lane & 15, Rg = lane >> 4;
      *(f32x4*)&gates[(wn * 32 + c) * 68 + wb * 32 + Rg * 4] = a00;
      *(f32x4*)&gates[(wn * 32 + 16 + c) * 68 + wb * 32 + Rg * 4] = a01;
      *(f32x4*)&gates[(wn * 32 + c) * 68 + wb * 32 + 16 + Rg * 4] = a10;
      *(f32x4*)&gates[(wn * 32 + 16 + c) * 68 + wb * 32 + 16 + Rg * 4] = a11;
    }
    __syncthreads();

    // ---- activations + cell update (c in regs) + h store ----
    {
      int brel = tid & 63, jq = tid >> 6;
      int b = b0 + brel;
      int jb = j0 + jq * 4;
      f32x4 cnew;
      float hv[4];
#pragma unroll
      for (int i2 = 0; i2 < 4; ++i2) {
        int jr = jq * 4 + i2;
        float ip = gates[(4 * jr + 0) * 68 + brel];
        float fp = gates[(4 * jr + 1) * 68 + brel];
        float gp = gates[(4 * jr + 2) * 68 + brel];
        float op = gates[(4 * jr + 3) * 68 + brel];
        float ii = sigf(ip), ff = sigf(fp), gg = tanhfast(gp), oo = sigf(op);
        float cc = ff * creg[i2] + ii * gg;
        cnew[i2] = cc;
        hv[i2] = oo * tanhfast(cc);
      }
      creg = cnew;
      u16x4 h4 = {f2bf(hv[0]), f2bf(hv[1]), f2bf(hv[2]), f2bf(hv[3])};
      stq(hbuf + ((size_t)layer * 4 + (t & 3)) * 65536 + (size_t)b * H + jb,
          __builtin_bit_cast(u64, h4));
    }
    // drain stores, then publish own sentinel slot
    asm volatile("s_waitcnt vmcnt(0)" ::: "memory");
    __syncthreads();
    if (tid == 0) stw_agent(sent_own + ntile, (unsigned)(t + 1));
  }

  // ---- final projection by layer-3 WGs: 4 b each ----
  if (layer == 3) {
    if (tid == 0) {
      int it = 0;
      while (min16_agent(sent_own) < (unsigned)T) {
        if (++it > 32) __builtin_amdgcn_s_sleep(1);
      }
    }
    __syncthreads();
    asm volatile("" ::: "memory");
    {
      int bi = tid >> 6, gcol = tid & 63;
      int brow2 = b0 + ntile * 4 + bi;
      const unsigned short* hp = hbuf + ((size_t)3 * 4 + ((T - 1) & 3)) * 65536;
      u64 v = ldq((const u64*)(hp + (size_t)brow2 * 256 + gcol * 4));
      gates[bi * 260 + gcol * 4 + 0] = bf2f((unsigned short)v);
      gates[bi * 260 + gcol * 4 + 1] = bf2f((unsigned short)(v >> 16));
      gates[bi * 260 + gcol * 4 + 2] = bf2f((unsigned short)(v >> 32));
      gates[bi * 260 + gcol * 4 + 3] = bf2f((unsigned short)(v >> 48));
    }
    __syncthreads();
    if (tid < 4 * OUTD) {
      int o = tid % OUTD, bj = tid / OUTD;
      int b = b0 + ntile * 4 + bj;
      const float* wr = Wout + (size_t)o * H;
      const float* hr = &gates[bj * 260];
      float sum = bout[o];
#pragma unroll 8
      for (int j = 0; j < H; ++j) sum = fmaf(hr[j], wr[j], sum);
      out[b * OUTD + o] = sigf(sum);
    }
  }
}

extern "C" void kernel_launch(void* const* d_in, const int* in_sizes, int n_in,
                              void* d_out, int out_size, void* d_ws, size_t ws_size,
                              hipStream_t stream) {
  const float* x = (const float*)d_in[0];
  const float* Wih0 = (const float*)d_in[1];
  const float* WihRest = (const float*)d_in[2];
  const float* Whh = (const float*)d_in[3];
  const float* bih = (const float*)d_in[4];
  const float* bhh = (const float*)d_in[5];
  const float* Wout = (const float*)d_in[6];
  const float* bout = (const float*)d_in[7];
  float* out = (float*)d_out;
  char* ws = (char*)d_ws;

  unsigned* sent = (unsigned*)(ws + WS_SENT);
  unsigned short* hbuf = (unsigned short*)(ws + WS_HBUF);
  unsigned short* xbf = (unsigned short*)(ws + WS_XBF);
  unsigned short* wih0r = (unsigned short*)(ws + WS_WIH0);
  unsigned short* wihr = (unsigned short*)(ws + WS_WIHR);
  unsigned short* whhr = (unsigned short*)(ws + WS_WHHR);
  float* biasr = (float*)(ws + WS_BIAS);

  hipMemsetAsync(ws, 0, (size_t)WS_ZERO, stream);
  prep_x<<<2048, 256, 0, stream>>>(x, xbf);
  prep_w<<<2048, 256, 0, stream>>>(Wih0, WihRest, Whh, bih, bhh, wih0r, wihr, whhr, biasr);
  lstm_main<<<NWG, 256, 0, stream>>>(xbf, wih0r, wihr, whhr, biasr, Wout, bout, hbuf,
                                     sent, out);
}

// Round 9
// 4605.438 us; speedup vs baseline: 1.6237x; 1.6237x over previous
//
#include <hip/hip_runtime.h>
#include <stdint.h>

// LSTMModel: 4-layer LSTM (B=256,T=512,H=256,Din=28) + sigmoid proj (21)
// R8: R4's proven staging geometry (lane-adjacent 16B column granules,
// conflict-free LDS writes) + R7's safe wins: weights in registers,
// per-WG sentinel slots, tid0 cached polls + hot spin, t=0 rec skip.

#define B 256
#define T 512
#define H 256
#define DIN 28
#define NWG 256
#define OUTD 21

typedef __attribute__((ext_vector_type(8))) __bf16 bf16x8;
typedef __attribute__((ext_vector_type(4))) float f32x4;
typedef __attribute__((ext_vector_type(4))) unsigned short u16x4;
typedef unsigned long long u64;

// ---- workspace layout (bytes) ----
#define WS_SENT  0ull                                   // 32 grp * 16 u32 = 2 KB
#define WS_HBUF  2048ull                                // [l][slot4][b][j] bf16: 2 MB
#define WS_XBF   (WS_HBUF + 4ull*4*B*H*2)               // x bf16 [b][t][32]: 8 MB
#define WS_WIH0  (WS_XBF + (u64)B*T*32*2)
#define WS_WIHR  (WS_WIH0 + 1024ull*32*2)
#define WS_WHHR  (WS_WIHR + 3ull*1024*256*2)
#define WS_BIAS  (WS_WHHR + 4ull*1024*256*2)
#define WS_ZERO  2048ull                                // memset: sentinels only

__device__ __forceinline__ unsigned short f2bf(float f) {
  unsigned u = __builtin_bit_cast(unsigned, f);
  u += 0x7fffu + ((u >> 16) & 1u);
  return (unsigned short)(u >> 16);
}
__device__ __forceinline__ float bf2f(unsigned short v) {
  return __builtin_bit_cast(float, (unsigned)v << 16);
}
__device__ __forceinline__ float sigf(float x) { return 1.f / (1.f + __expf(-x)); }
__device__ __forceinline__ float tanhfast(float x) {
  float e = __expf(2.f * x);
  return 1.f - 2.f / (e + 1.f);
}
__device__ __forceinline__ bf16x8 ldb8(const void* p) { return *(const bf16x8*)p; }
__device__ __forceinline__ u64 ldq(const u64* p) {
  return __hip_atomic_load(p, __ATOMIC_RELAXED, __HIP_MEMORY_SCOPE_AGENT);
}
__device__ __forceinline__ void stq(void* p, u64 v) {
  __hip_atomic_store((u64*)p, v, __ATOMIC_RELAXED, __HIP_MEMORY_SCOPE_AGENT);
}
__device__ __forceinline__ void stw_agent(unsigned* p, unsigned v) {
  __hip_atomic_store(p, v, __ATOMIC_RELAXED, __HIP_MEMORY_SCOPE_AGENT);
}
__device__ __forceinline__ unsigned umin2(unsigned a, unsigned b) { return a < b ? a : b; }
__device__ __forceinline__ unsigned min16_agent(const unsigned* p) {
  unsigned m = 0xFFFFFFFFu;
  const u64* q = (const u64*)p;
#pragma unroll
  for (int i = 0; i < 8; ++i) {
    u64 v = ldq(q + i);
    m = umin2(m, umin2((unsigned)v, (unsigned)(v >> 32)));
  }
  return m;
}

// ---------------- prep kernels ----------------
__global__ void prep_x(const float* __restrict__ x, unsigned short* __restrict__ xbf) {
  int tot = B * T * 32;
  for (int idx = blockIdx.x * blockDim.x + threadIdx.x; idx < tot;
       idx += gridDim.x * blockDim.x) {
    int kk = idx & 31;
    int bt = idx >> 5;
    float v = (kk < DIN) ? x[(size_t)bt * DIN + kk] : 0.f;
    xbf[idx] = f2bf(v);
  }
}

__global__ void prep_w(const float* __restrict__ wih0, const float* __restrict__ wihrest,
                       const float* __restrict__ whh, const float* __restrict__ bih,
                       const float* __restrict__ bhh,
                       unsigned short* __restrict__ wih0r, unsigned short* __restrict__ wihr,
                       unsigned short* __restrict__ whhr, float* __restrict__ biasr) {
  const int R0 = 1024 * 32, R1 = 3 * 1024 * 256, R2 = 4 * 1024 * 256, R3 = 4 * 1024;
  int tot = R0 + R1 + R2 + R3;
  for (int idx = blockIdx.x * blockDim.x + threadIdx.x; idx < tot;
       idx += gridDim.x * blockDim.x) {
    if (idx < R0) {
      int k = idx & 31, np = idx >> 5, g = np & 3, j = np >> 2;
      wih0r[idx] = f2bf(k < DIN ? wih0[(size_t)(g * 256 + j) * DIN + k] : 0.f);
    } else if (idx < R0 + R1) {
      int i = idx - R0;
      int k = i & 255, r = i >> 8, np = r & 1023, l = r >> 10, g = np & 3, j = np >> 2;
      wihr[i] = f2bf(wihrest[((size_t)l * 1024 + g * 256 + j) * 256 + k]);
    } else if (idx < R0 + R1 + R2) {
      int i = idx - R0 - R1;
      int k = i & 255, r = i >> 8, np = r & 1023, l = r >> 10, g = np & 3, j = np >> 2;
      whhr[i] = f2bf(whh[((size_t)l * 1024 + g * 256 + j) * 256 + k]);
    } else {
      int i = idx - R0 - R1 - R2;
      int np = i & 1023, l = i >> 10, g = np & 3, j = np >> 2;
      biasr[i] = bih[l * 1024 + g * 256 + j] + bhh[l * 1024 + g * 256 + j];
    }
  }
}

// ---------------- main persistent kernel ----------------
__device__ __forceinline__ void mstep2(const unsigned char* Ap, int kb, int ar0, int ar1,
                                       bf16x8 b0, bf16x8 b1, f32x4& a00, f32x4& a01,
                                       f32x4& a10, f32x4& a11) {
  bf16x8 a0 = *(const bf16x8*)(Ap + ar0 * 1024 + (kb ^ ((ar0 & 15) << 4)));
  bf16x8 a1 = *(const bf16x8*)(Ap + ar1 * 1024 + (kb ^ ((ar1 & 15) << 4)));
  a00 = __builtin_amdgcn_mfma_f32_16x16x32_bf16(a0, b0, a00, 0, 0, 0);
  a01 = __builtin_amdgcn_mfma_f32_16x16x32_bf16(a0, b1, a01, 0, 0, 0);
  a10 = __builtin_amdgcn_mfma_f32_16x16x32_bf16(a1, b0, a10, 0, 0, 0);
  a11 = __builtin_amdgcn_mfma_f32_16x16x32_bf16(a1, b1, a11, 0, 0, 0);
}

__launch_bounds__(256, 1)
__global__ void lstm_main(const unsigned short* __restrict__ xbf,
                          const unsigned short* __restrict__ wih0r,
                          const unsigned short* __restrict__ wihr,
                          const unsigned short* __restrict__ whhr,
                          const float* __restrict__ biasr,
                          const float* __restrict__ Wout, const float* __restrict__ bout,
                          unsigned short* __restrict__ hbuf, unsigned* __restrict__ sent,
                          float* __restrict__ out) {
  __shared__ unsigned char Ap[64 * 1024];   // A panel: 64 b-rows x 1KB, XOR-swizzled
  __shared__ float gates[64 * 68];          // [n'rel][brel] exchange, stride 68

  const int tid = threadIdx.x;
  const int lane = tid & 63;
  const int w = tid >> 6;
  const int wb = w >> 1, wn = w & 1;
  const int bid = blockIdx.x;
  const int layer = (bid & 7) >> 1;
  const int wgl = ((bid >> 3) << 1) | (bid & 1);
  const int b0g = wgl >> 4;
  const int b0 = b0g * 64;
  const int ntile = wgl & 15;
  const int n0 = ntile * 64;
  const int j0 = ntile * 16;
  const int mygrp = layer * 4 + b0g;

  unsigned* sent_own = sent + mygrp * 16;
  const unsigned* sent_up = (layer > 0) ? sent + (mygrp - 4) * 16 : sent_own;
  const unsigned* sent_dn = (layer < 3) ? sent + (mygrp + 4) * 16 : sent_own;

  // ---- weights -> registers (B fragments), bias ----
  const int brow0 = wn * 32 + (lane & 15);
  const int brow1 = brow0 + 16;
  const int koff8 = (lane >> 4) * 8;     // short offset within 32-K chunk
  const int akoff2 = (lane >> 4) * 16;   // byte offset
  bf16x8 bA[16], bB[16];
  if (layer == 0) {
    bA[0] = *(const bf16x8*)(wih0r + (size_t)(n0 + brow0) * 32 + koff8);
    bB[0] = *(const bf16x8*)(wih0r + (size_t)(n0 + brow1) * 32 + koff8);
#pragma unroll
    for (int kk = 0; kk < 8; ++kk) {
      bA[1 + kk] = *(const bf16x8*)(whhr + (size_t)(n0 + brow0) * 256 + kk * 32 + koff8);
      bB[1 + kk] = *(const bf16x8*)(whhr + (size_t)(n0 + brow1) * 256 + kk * 32 + koff8);
    }
  } else {
#pragma unroll
    for (int kk = 0; kk < 8; ++kk) {
      bA[kk] = *(const bf16x8*)(wihr + ((size_t)(layer - 1) * 1024 + n0 + brow0) * 256 +
                                kk * 32 + koff8);
      bB[kk] = *(const bf16x8*)(wihr + ((size_t)(layer - 1) * 1024 + n0 + brow1) * 256 +
                                kk * 32 + koff8);
      bA[8 + kk] = *(const bf16x8*)(whhr + ((size_t)layer * 1024 + n0 + brow0) * 256 +
                                    kk * 32 + koff8);
      bB[8 + kk] = *(const bf16x8*)(whhr + ((size_t)layer * 1024 + n0 + brow1) * 256 +
                                    kk * 32 + koff8);
    }
  }
  const float bv0 = biasr[layer * 1024 + n0 + wn * 32 + (lane & 15)];
  const float bv1 = biasr[layer * 1024 + n0 + wn * 32 + 16 + (lane & 15)];

  const int arow0 = wb * 32 + (lane & 15);
  const int arow1 = arow0 + 16;
  const int stg_blk = tid & 63;   // 16B column granule (lane-adjacent!)
  const int stg_r0 = tid >> 6;    // base row, stride 4

  f32x4 creg = {0.f, 0.f, 0.f, 0.f};
  unsigned cache_up = 0, cache_dn = 0;

  for (int t = 0; t < T; ++t) {
    // ---- gating: tid0 polls sentinel lines (cached for ff/bp edges) ----
    if (tid == 0) {
      int it = 0;
      if (t > 0) {
        while (min16_agent(sent_own) < (unsigned)t) {
          if (++it > 32) __builtin_amdgcn_s_sleep(1);
        }
      }
      if (layer > 0 && cache_up < (unsigned)(t + 1)) {
        while ((cache_up = min16_agent(sent_up)) < (unsigned)(t + 1)) {
          if (++it > 32) __builtin_amdgcn_s_sleep(1);
        }
      }
      if (layer < 3 && t >= 4 && cache_dn < (unsigned)(t - 3)) {
        while ((cache_dn = min16_agent(sent_dn)) < (unsigned)(t - 3)) {
          if (++it > 32) __builtin_amdgcn_s_sleep(1);
        }
      }
    }
    __syncthreads();
    asm volatile("" ::: "memory");

    // ---- cooperative staging: thread = one 16B column x 16 rows ----
    // layer0 panel row: [x 64B | rec 512B]  granules: 0-3 x, 4-35 rec
    // layer>0 row:      [prev 512B | rec 512B] granules: 0-31 prev, 32-63 rec
    const unsigned short* hbR = hbuf + ((size_t)layer * 4 + ((t - 1) & 3)) * 65536;
    u64 qa[16], qb[16];
    bool wr = false;
    if (layer == 0) {
      if (stg_blk < 4) {
        wr = true;
#pragma unroll
        for (int it = 0; it < 16; ++it) {
          int row = b0 + stg_r0 + it * 4;
          bf16x8 v = ldb8(xbf + ((size_t)row * T + t) * 32 + stg_blk * 8);
          qa[it] = ((const u64*)&v)[0];
          qb[it] = ((const u64*)&v)[1];
        }
      } else if (stg_blk < 36 && t > 0) {
        wr = true;
#pragma unroll
        for (int it = 0; it < 16; ++it) {
          int row = b0 + stg_r0 + it * 4;
          const u64* s = (const u64*)(hbR + (size_t)row * 256 + (stg_blk - 4) * 8);
          qa[it] = ldq(s);
          qb[it] = ldq(s + 1);
        }
      }
    } else {
      const unsigned short* hbP = hbuf + ((size_t)(layer - 1) * 4 + (t & 3)) * 65536;
      if (stg_blk < 32) {
        wr = true;
#pragma unroll
        for (int it = 0; it < 16; ++it) {
          int row = b0 + stg_r0 + it * 4;
          const u64* s = (const u64*)(hbP + (size_t)row * 256 + stg_blk * 8);
          qa[it] = ldq(s);
          qb[it] = ldq(s + 1);
        }
      } else if (t > 0) {
        wr = true;
#pragma unroll
        for (int it = 0; it < 16; ++it) {
          int row = b0 + stg_r0 + it * 4;
          const u64* s = (const u64*)(hbR + (size_t)row * 256 + (stg_blk - 32) * 8);
          qa[it] = ldq(s);
          qb[it] = ldq(s + 1);
        }
      }
    }
    __builtin_amdgcn_sched_barrier(0);
    if (wr) {
#pragma unroll
      for (int it = 0; it < 16; ++it) {
        int row = stg_r0 + it * 4;
        uint4 v;
        ((u64*)&v)[0] = qa[it];
        ((u64*)&v)[1] = qb[it];
        *(uint4*)(Ap + row * 1024 + ((stg_blk * 16) ^ ((row & 15) << 4))) = v;
      }
    }
    __syncthreads();

    // ---- MFMAs (A from LDS, B from registers) ----
    f32x4 a00 = {bv0, bv0, bv0, bv0};
    f32x4 a01 = {bv1, bv1, bv1, bv1};
    f32x4 a10 = a00, a11 = a01;
    if (layer == 0) {
      mstep2(Ap, akoff2, arow0, arow1, bA[0], bB[0], a00, a01, a10, a11);
      if (t > 0) {
#pragma unroll
        for (int kk = 0; kk < 8; ++kk)
          mstep2(Ap, 64 + kk * 64 + akoff2, arow0, arow1, bA[1 + kk], bB[1 + kk],
                 a00, a01, a10, a11);
      }
    } else {
#pragma unroll
      for (int kk = 0; kk < 8; ++kk)
        mstep2(Ap, kk * 64 + akoff2, arow0, arow1, bA[kk], bB[kk], a00, a01, a10, a11);
      if (t > 0) {
#pragma unroll
        for (int kk = 0; kk < 8; ++kk)
          mstep2(Ap, 512 + kk * 64 + akoff2, arow0, arow1, bA[8 + kk], bB[8 + kk],
                 a00, a01, a10, a11);
      }
    }

    // ---- scatter acc frags to gates[n'rel][brel] ----
    {
      int c = lane & 15, Rg = lane >> 4;
      *(f32x4*)&gates[(wn * 32 + c) * 68 + wb * 32 + Rg * 4] = a00;
      *(f32x4*)&gates[(wn * 32 + 16 + c) * 68 + wb * 32 + Rg * 4] = a01;
      *(f32x4*)&gates[(wn * 32 + c) * 68 + wb * 32 + 16 + Rg * 4] = a10;
      *(f32x4*)&gates[(wn * 32 + 16 + c) * 68 + wb * 32 + 16 + Rg * 4] = a11;
    }
    __syncthreads();

    // ---- activations + cell update (c in regs) + h store ----
    {
      int brel = tid & 63, jq = tid >> 6;
      int b = b0 + brel;
      int jb = j0 + jq * 4;
      f32x4 cnew;
      float hv[4];
#pragma unroll
      for (int i2 = 0; i2 < 4; ++i2) {
        int jr = jq * 4 + i2;
        float ip = gates[(4 * jr + 0) * 68 + brel];
        float fp = gates[(4 * jr + 1) * 68 + brel];
        float gp = gates[(4 * jr + 2) * 68 + brel];
        float op = gates[(4 * jr + 3) * 68 + brel];
        float ii = sigf(ip), ff = sigf(fp), gg = tanhfast(gp), oo = sigf(op);
        float cc = ff * creg[i2] + ii * gg;
        cnew[i2] = cc;
        hv[i2] = oo * tanhfast(cc);
      }
      creg = cnew;
      u16x4 h4 = {f2bf(hv[0]), f2bf(hv[1]), f2bf(hv[2]), f2bf(hv[3])};
      stq(hbuf + ((size_t)layer * 4 + (t & 3)) * 65536 + (size_t)b * H + jb,
          __builtin_bit_cast(u64, h4));
    }
    // drain stores, then publish own sentinel slot
    asm volatile("s_waitcnt vmcnt(0)" ::: "memory");
    __syncthreads();
    if (tid == 0) stw_agent(sent_own + ntile, (unsigned)(t + 1));
  }

  // ---- final projection by layer-3 WGs: 4 b each ----
  if (layer == 3) {
    if (tid == 0) {
      int it = 0;
      while (min16_agent(sent_own) < (unsigned)T) {
        if (++it > 32) __builtin_amdgcn_s_sleep(1);
      }
    }
    __syncthreads();
    asm volatile("" ::: "memory");
    {
      int bi = tid >> 6, gcol = tid & 63;
      int brow2 = b0 + ntile * 4 + bi;
      const unsigned short* hp = hbuf + ((size_t)3 * 4 + ((T - 1) & 3)) * 65536;
      u64 v = ldq((const u64*)(hp + (size_t)brow2 * 256 + gcol * 4));
      gates[bi * 260 + gcol * 4 + 0] = bf2f((unsigned short)v);
      gates[bi * 260 + gcol * 4 + 1] = bf2f((unsigned short)(v >> 16));
      gates[bi * 260 + gcol * 4 + 2] = bf2f((unsigned short)(v >> 32));
      gates[bi * 260 + gcol * 4 + 3] = bf2f((unsigned short)(v >> 48));
    }
    __syncthreads();
    if (tid < 4 * OUTD) {
      int o = tid % OUTD, bj = tid / OUTD;
      int b = b0 + ntile * 4 + bj;
      const float* wr = Wout + (size_t)o * H;
      const float* hr = &gates[bj * 260];
      float sum = bout[o];
#pragma unroll 8
      for (int j = 0; j < H; ++j) sum = fmaf(hr[j], wr[j], sum);
      out[b * OUTD + o] = sigf(sum);
    }
  }
}

extern "C" void kernel_launch(void* const* d_in, const int* in_sizes, int n_in,
                              void* d_out, int out_size, void* d_ws, size_t ws_size,
                              hipStream_t stream) {
  const float* x = (const float*)d_in[0];
  const float* Wih0 = (const float*)d_in[1];
  const float* WihRest = (const float*)d_in[2];
  const float* Whh = (const float*)d_in[3];
  const float* bih = (const float*)d_in[4];
  const float* bhh = (const float*)d_in[5];
  const float* Wout = (const float*)d_in[6];
  const float* bout = (const float*)d_in[7];
  float* out = (float*)d_out;
  char* ws = (char*)d_ws;

  unsigned* sent = (unsigned*)(ws + WS_SENT);
  unsigned short* hbuf = (unsigned short*)(ws + WS_HBUF);
  unsigned short* xbf = (unsigned short*)(ws + WS_XBF);
  unsigned short* wih0r = (unsigned short*)(ws + WS_WIH0);
  unsigned short* wihr = (unsigned short*)(ws + WS_WIHR);
  unsigned short* whhr = (unsigned short*)(ws + WS_WHHR);
  float* biasr = (float*)(ws + WS_BIAS);

  hipMemsetAsync(ws, 0, (size_t)WS_ZERO, stream);
  prep_x<<<2048, 256, 0, stream>>>(x, xbf);
  prep_w<<<2048, 256, 0, stream>>>(Wih0, WihRest, Whh, bih, bhh, wih0r, wihr, whhr, biasr);
  lstm_main<<<NWG, 256, 0, stream>>>(xbf, wih0r, wihr, whhr, biasr, Wout, bout, hbuf,
                                     sent, out);
}

// Round 10
// 3490.013 us; speedup vs baseline: 2.1427x; 1.3196x over previous
//
#include <hip/hip_runtime.h>
#include <stdint.h>

// LSTMModel: 4-layer LSTM (B=256,T=512,H=256,Din=28) + sigmoid proj (21)
// R9: R4's proven sync (per-(grp,t) atomicAdd counter flags, single-word
// paced polls, no hot spin) + R8's proven conflict-free staging geometry
// + weights in registers + t=0 rec skip.

#define B 256
#define T 512
#define H 256
#define DIN 28
#define NWG 256
#define OUTD 21

typedef __attribute__((ext_vector_type(8))) __bf16 bf16x8;
typedef __attribute__((ext_vector_type(4))) float f32x4;
typedef __attribute__((ext_vector_type(4))) unsigned short u16x4;
typedef unsigned long long u64;

// ---- workspace layout (bytes) ----
#define WS_FLAGS 0ull                                   // 32 grp * 512 t * u32 = 64 KB
#define WS_HBUF  65536ull                               // [l][slot4][b][j] bf16: 2 MB
#define WS_XBF   (WS_HBUF + 4ull*4*B*H*2)               // x bf16 [b][t][32]: 8 MB
#define WS_WIH0  (WS_XBF + (u64)B*T*32*2)
#define WS_WIHR  (WS_WIH0 + 1024ull*32*2)
#define WS_WHHR  (WS_WIHR + 3ull*1024*256*2)
#define WS_BIAS  (WS_WHHR + 4ull*1024*256*2)
#define WS_ZERO  65536ull                               // memset: flags only

__device__ __forceinline__ unsigned short f2bf(float f) {
  unsigned u = __builtin_bit_cast(unsigned, f);
  u += 0x7fffu + ((u >> 16) & 1u);
  return (unsigned short)(u >> 16);
}
__device__ __forceinline__ float bf2f(unsigned short v) {
  return __builtin_bit_cast(float, (unsigned)v << 16);
}
__device__ __forceinline__ float sigf(float x) { return 1.f / (1.f + __expf(-x)); }
__device__ __forceinline__ float tanhfast(float x) {
  float e = __expf(2.f * x);
  return 1.f - 2.f / (e + 1.f);
}
__device__ __forceinline__ bf16x8 ldb8(const void* p) { return *(const bf16x8*)p; }
__device__ __forceinline__ u64 ldq(const u64* p) {
  return __hip_atomic_load(p, __ATOMIC_RELAXED, __HIP_MEMORY_SCOPE_AGENT);
}
__device__ __forceinline__ void stq(void* p, u64 v) {
  __hip_atomic_store((u64*)p, v, __ATOMIC_RELAXED, __HIP_MEMORY_SCOPE_AGENT);
}
__device__ __forceinline__ unsigned ldflag(const unsigned* f) {
  return __hip_atomic_load(f, __ATOMIC_RELAXED, __HIP_MEMORY_SCOPE_AGENT);
}

// ---------------- prep kernels ----------------
__global__ void prep_x(const float* __restrict__ x, unsigned short* __restrict__ xbf) {
  int tot = B * T * 32;
  for (int idx = blockIdx.x * blockDim.x + threadIdx.x; idx < tot;
       idx += gridDim.x * blockDim.x) {
    int kk = idx & 31;
    int bt = idx >> 5;
    float v = (kk < DIN) ? x[(size_t)bt * DIN + kk] : 0.f;
    xbf[idx] = f2bf(v);
  }
}

__global__ void prep_w(const float* __restrict__ wih0, const float* __restrict__ wihrest,
                       const float* __restrict__ whh, const float* __restrict__ bih,
                       const float* __restrict__ bhh,
                       unsigned short* __restrict__ wih0r, unsigned short* __restrict__ wihr,
                       unsigned short* __restrict__ whhr, float* __restrict__ biasr) {
  const int R0 = 1024 * 32, R1 = 3 * 1024 * 256, R2 = 4 * 1024 * 256, R3 = 4 * 1024;
  int tot = R0 + R1 + R2 + R3;
  for (int idx = blockIdx.x * blockDim.x + threadIdx.x; idx < tot;
       idx += gridDim.x * blockDim.x) {
    if (idx < R0) {
      int k = idx & 31, np = idx >> 5, g = np & 3, j = np >> 2;
      wih0r[idx] = f2bf(k < DIN ? wih0[(size_t)(g * 256 + j) * DIN + k] : 0.f);
    } else if (idx < R0 + R1) {
      int i = idx - R0;
      int k = i & 255, r = i >> 8, np = r & 1023, l = r >> 10, g = np & 3, j = np >> 2;
      wihr[i] = f2bf(wihrest[((size_t)l * 1024 + g * 256 + j) * 256 + k]);
    } else if (idx < R0 + R1 + R2) {
      int i = idx - R0 - R1;
      int k = i & 255, r = i >> 8, np = r & 1023, l = r >> 10, g = np & 3, j = np >> 2;
      whhr[i] = f2bf(whh[((size_t)l * 1024 + g * 256 + j) * 256 + k]);
    } else {
      int i = idx - R0 - R1 - R2;
      int np = i & 1023, l = i >> 10, g = np & 3, j = np >> 2;
      biasr[i] = bih[l * 1024 + g * 256 + j] + bhh[l * 1024 + g * 256 + j];
    }
  }
}

// ---------------- main persistent kernel ----------------
__device__ __forceinline__ void mstep2(const unsigned char* Ap, int kb, int ar0, int ar1,
                                       bf16x8 b0, bf16x8 b1, f32x4& a00, f32x4& a01,
                                       f32x4& a10, f32x4& a11) {
  bf16x8 a0 = *(const bf16x8*)(Ap + ar0 * 1024 + (kb ^ ((ar0 & 15) << 4)));
  bf16x8 a1 = *(const bf16x8*)(Ap + ar1 * 1024 + (kb ^ ((ar1 & 15) << 4)));
  a00 = __builtin_amdgcn_mfma_f32_16x16x32_bf16(a0, b0, a00, 0, 0, 0);
  a01 = __builtin_amdgcn_mfma_f32_16x16x32_bf16(a0, b1, a01, 0, 0, 0);
  a10 = __builtin_amdgcn_mfma_f32_16x16x32_bf16(a1, b0, a10, 0, 0, 0);
  a11 = __builtin_amdgcn_mfma_f32_16x16x32_bf16(a1, b1, a11, 0, 0, 0);
}

__launch_bounds__(256, 1)
__global__ void lstm_main(const unsigned short* __restrict__ xbf,
                          const unsigned short* __restrict__ wih0r,
                          const unsigned short* __restrict__ wihr,
                          const unsigned short* __restrict__ whhr,
                          const float* __restrict__ biasr,
                          const float* __restrict__ Wout, const float* __restrict__ bout,
                          unsigned short* __restrict__ hbuf, unsigned* __restrict__ flags,
                          float* __restrict__ out) {
  __shared__ unsigned char Ap[64 * 1024];   // A panel: 64 b-rows x 1KB, XOR-swizzled
  __shared__ float gates[64 * 68];          // [n'rel][brel] exchange, stride 68

  const int tid = threadIdx.x;
  const int lane = tid & 63;
  const int w = tid >> 6;
  const int wb = w >> 1, wn = w & 1;
  const int bid = blockIdx.x;
  const int layer = (bid & 7) >> 1;
  const int wgl = ((bid >> 3) << 1) | (bid & 1);
  const int b0g = wgl >> 4;
  const int b0 = b0g * 64;
  const int ntile = wgl & 15;
  const int n0 = ntile * 64;
  const int j0 = ntile * 16;
  const int mygrp = layer * 4 + b0g;

  // ---- weights -> registers (B fragments), bias ----
  const int brow0 = wn * 32 + (lane & 15);
  const int brow1 = brow0 + 16;
  const int koff8 = (lane >> 4) * 8;     // short offset within 32-K chunk
  const int akoff2 = (lane >> 4) * 16;   // byte offset
  bf16x8 bA[16], bB[16];
  if (layer == 0) {
    bA[0] = *(const bf16x8*)(wih0r + (size_t)(n0 + brow0) * 32 + koff8);
    bB[0] = *(const bf16x8*)(wih0r + (size_t)(n0 + brow1) * 32 + koff8);
#pragma unroll
    for (int kk = 0; kk < 8; ++kk) {
      bA[1 + kk] = *(const bf16x8*)(whhr + (size_t)(n0 + brow0) * 256 + kk * 32 + koff8);
      bB[1 + kk] = *(const bf16x8*)(whhr + (size_t)(n0 + brow1) * 256 + kk * 32 + koff8);
    }
  } else {
#pragma unroll
    for (int kk = 0; kk < 8; ++kk) {
      bA[kk] = *(const bf16x8*)(wihr + ((size_t)(layer - 1) * 1024 + n0 + brow0) * 256 +
                                kk * 32 + koff8);
      bB[kk] = *(const bf16x8*)(wihr + ((size_t)(layer - 1) * 1024 + n0 + brow1) * 256 +
                                kk * 32 + koff8);
      bA[8 + kk] = *(const bf16x8*)(whhr + ((size_t)layer * 1024 + n0 + brow0) * 256 +
                                    kk * 32 + koff8);
      bB[8 + kk] = *(const bf16x8*)(whhr + ((size_t)layer * 1024 + n0 + brow1) * 256 +
                                    kk * 32 + koff8);
    }
  }
  const float bv0 = biasr[layer * 1024 + n0 + wn * 32 + (lane & 15)];
  const float bv1 = biasr[layer * 1024 + n0 + wn * 32 + 16 + (lane & 15)];

  const int arow0 = wb * 32 + (lane & 15);
  const int arow1 = arow0 + 16;
  const int stg_blk = tid & 63;   // 16B column granule (lane-adjacent)
  const int stg_r0 = tid >> 6;    // base row, stride 4

  f32x4 creg = {0.f, 0.f, 0.f, 0.f};

  for (int t = 0; t < T; ++t) {
    // ---- gating: tid0 polls 3 single u32 flags, sleep-paced (R4-proven) ----
    if (tid == 0) {
      const unsigned* frec = (t > 0) ? &flags[mygrp * 512 + (t - 1)] : nullptr;
      const unsigned* fprev = (layer > 0) ? &flags[(mygrp - 4) * 512 + t] : nullptr;
      const unsigned* fdown =
          (layer < 3 && t >= 4) ? &flags[(mygrp + 4) * 512 + (t - 4)] : nullptr;
      for (;;) {
        unsigned a = frec ? ldflag(frec) : 16u;
        unsigned b = fprev ? ldflag(fprev) : 16u;
        unsigned c = fdown ? ldflag(fdown) : 16u;
        if (a >= 16u && b >= 16u && c >= 16u) break;
        __builtin_amdgcn_s_sleep(1);
      }
    }
    __syncthreads();
    asm volatile("" ::: "memory");

    // ---- cooperative staging: thread = one 16B column x 16 rows ----
    // layer0 row: [x 64B | rec 512B]  granules: 0-3 x, 4-35 rec
    // layer>0 row: [prev 512B | rec 512B] granules: 0-31 prev, 32-63 rec
    const unsigned short* hbR = hbuf + ((size_t)layer * 4 + ((t - 1) & 3)) * 65536;
    u64 qa[16], qb[16];
    bool wr = false;
    if (layer == 0) {
      if (stg_blk < 4) {
        wr = true;
#pragma unroll
        for (int it = 0; it < 16; ++it) {
          int row = b0 + stg_r0 + it * 4;
          bf16x8 v = ldb8(xbf + ((size_t)row * T + t) * 32 + stg_blk * 8);
          qa[it] = ((const u64*)&v)[0];
          qb[it] = ((const u64*)&v)[1];
        }
      } else if (stg_blk < 36 && t > 0) {
        wr = true;
#pragma unroll
        for (int it = 0; it < 16; ++it) {
          int row = b0 + stg_r0 + it * 4;
          const u64* s = (const u64*)(hbR + (size_t)row * 256 + (stg_blk - 4) * 8);
          qa[it] = ldq(s);
          qb[it] = ldq(s + 1);
        }
      }
    } else {
      const unsigned short* hbP = hbuf + ((size_t)(layer - 1) * 4 + (t & 3)) * 65536;
      if (stg_blk < 32) {
        wr = true;
#pragma unroll
        for (int it = 0; it < 16; ++it) {
          int row = b0 + stg_r0 + it * 4;
          const u64* s = (const u64*)(hbP + (size_t)row * 256 + stg_blk * 8);
          qa[it] = ldq(s);
          qb[it] = ldq(s + 1);
        }
      } else if (t > 0) {
        wr = true;
#pragma unroll
        for (int it = 0; it < 16; ++it) {
          int row = b0 + stg_r0 + it * 4;
          const u64* s = (const u64*)(hbR + (size_t)row * 256 + (stg_blk - 32) * 8);
          qa[it] = ldq(s);
          qb[it] = ldq(s + 1);
        }
      }
    }
    __builtin_amdgcn_sched_barrier(0);
    if (wr) {
#pragma unroll
      for (int it = 0; it < 16; ++it) {
        int row = stg_r0 + it * 4;
        uint4 v;
        ((u64*)&v)[0] = qa[it];
        ((u64*)&v)[1] = qb[it];
        *(uint4*)(Ap + row * 1024 + ((stg_blk * 16) ^ ((row & 15) << 4))) = v;
      }
    }
    __syncthreads();

    // ---- MFMAs (A from LDS, B from registers) ----
    f32x4 a00 = {bv0, bv0, bv0, bv0};
    f32x4 a01 = {bv1, bv1, bv1, bv1};
    f32x4 a10 = a00, a11 = a01;
    if (layer == 0) {
      mstep2(Ap, akoff2, arow0, arow1, bA[0], bB[0], a00, a01, a10, a11);
      if (t > 0) {
#pragma unroll
        for (int kk = 0; kk < 8; ++kk)
          mstep2(Ap, 64 + kk * 64 + akoff2, arow0, arow1, bA[1 + kk], bB[1 + kk],
                 a00, a01, a10, a11);
      }
    } else {
#pragma unroll
      for (int kk = 0; kk < 8; ++kk)
        mstep2(Ap, kk * 64 + akoff2, arow0, arow1, bA[kk], bB[kk], a00, a01, a10, a11);
      if (t > 0) {
#pragma unroll
        for (int kk = 0; kk < 8; ++kk)
          mstep2(Ap, 512 + kk * 64 + akoff2, arow0, arow1, bA[8 + kk], bB[8 + kk],
                 a00, a01, a10, a11);
      }
    }

    // ---- scatter acc frags to gates[n'rel][brel] ----
    {
      int c = lane & 15, Rg = lane >> 4;
      *(f32x4*)&gates[(wn * 32 + c) * 68 + wb * 32 + Rg * 4] = a00;
      *(f32x4*)&gates[(wn * 32 + 16 + c) * 68 + wb * 32 + Rg * 4] = a01;
      *(f32x4*)&gates[(wn * 32 + c) * 68 + wb * 32 + 16 + Rg * 4] = a10;
      *(f32x4*)&gates[(wn * 32 + 16 + c) * 68 + wb * 32 + 16 + Rg * 4] = a11;
    }
    __syncthreads();

    // ---- activations + cell update (c in regs) + h store ----
    {
      int brel = tid & 63, jq = tid >> 6;
      int b = b0 + brel;
      int jb = j0 + jq * 4;
      f32x4 cnew;
      float hv[4];
#pragma unroll
      for (int i2 = 0; i2 < 4; ++i2) {
        int jr = jq * 4 + i2;
        float ip = gates[(4 * jr + 0) * 68 + brel];
        float fp = gates[(4 * jr + 1) * 68 + brel];
        float gp = gates[(4 * jr + 2) * 68 + brel];
        float op = gates[(4 * jr + 3) * 68 + brel];
        float ii = sigf(ip), ff = sigf(fp), gg = tanhfast(gp), oo = sigf(op);
        float cc = ff * creg[i2] + ii * gg;
        cnew[i2] = cc;
        hv[i2] = oo * tanhfast(cc);
      }
      creg = cnew;
      u16x4 h4 = {f2bf(hv[0]), f2bf(hv[1]), f2bf(hv[2]), f2bf(hv[3])};
      stq(hbuf + ((size_t)layer * 4 + (t & 3)) * 65536 + (size_t)b * H + jb,
          __builtin_bit_cast(u64, h4));
    }
    // drain stores, then publish (fire-and-forget atomicAdd, R4-proven)
    asm volatile("s_waitcnt vmcnt(0)" ::: "memory");
    __syncthreads();
    if (tid == 0)
      __hip_atomic_fetch_add(&flags[mygrp * 512 + t], 1u, __ATOMIC_RELAXED,
                             __HIP_MEMORY_SCOPE_AGENT);
  }

  // ---- final projection by layer-3 WGs: 4 b each ----
  if (layer == 3) {
    if (tid == 0) {
      while (ldflag(&flags[mygrp * 512 + (T - 1)]) < 16u) __builtin_amdgcn_s_sleep(1);
    }
    __syncthreads();
    asm volatile("" ::: "memory");
    {
      int bi = tid >> 6, gcol = tid & 63;
      int brow2 = b0 + ntile * 4 + bi;
      const unsigned short* hp = hbuf + ((size_t)3 * 4 + ((T - 1) & 3)) * 65536;
      u64 v = ldq((const u64*)(hp + (size_t)brow2 * 256 + gcol * 4));
      gates[bi * 260 + gcol * 4 + 0] = bf2f((unsigned short)v);
      gates[bi * 260 + gcol * 4 + 1] = bf2f((unsigned short)(v >> 16));
      gates[bi * 260 + gcol * 4 + 2] = bf2f((unsigned short)(v >> 32));
      gates[bi * 260 + gcol * 4 + 3] = bf2f((unsigned short)(v >> 48));
    }
    __syncthreads();
    if (tid < 4 * OUTD) {
      int o = tid % OUTD, bj = tid / OUTD;
      int b = b0 + ntile * 4 + bj;
      const float* wr = Wout + (size_t)o * H;
      const float* hr = &gates[bj * 260];
      float sum = bout[o];
#pragma unroll 8
      for (int j = 0; j < H; ++j) sum = fmaf(hr[j], wr[j], sum);
      out[b * OUTD + o] = sigf(sum);
    }
  }
}

extern "C" void kernel_launch(void* const* d_in, const int* in_sizes, int n_in,
                              void* d_out, int out_size, void* d_ws, size_t ws_size,
                              hipStream_t stream) {
  const float* x = (const float*)d_in[0];
  const float* Wih0 = (const float*)d_in[1];
  const float* WihRest = (const float*)d_in[2];
  const float* Whh = (const float*)d_in[3];
  const float* bih = (const float*)d_in[4];
  const float* bhh = (const float*)d_in[5];
  const float* Wout = (const float*)d_in[6];
  const float* bout = (const float*)d_in[7];
  float* out = (float*)d_out;
  char* ws = (char*)d_ws;

  unsigned* flags = (unsigned*)(ws + WS_FLAGS);
  unsigned short* hbuf = (unsigned short*)(ws + WS_HBUF);
  unsigned short* xbf = (unsigned short*)(ws + WS_XBF);
  unsigned short* wih0r = (unsigned short*)(ws + WS_WIH0);
  unsigned short* wihr = (unsigned short*)(ws + WS_WIHR);
  unsigned short* whhr = (unsigned short*)(ws + WS_WHHR);
  float* biasr = (float*)(ws + WS_BIAS);

  hipMemsetAsync(ws, 0, (size_t)WS_ZERO, stream);
  prep_x<<<2048, 256, 0, stream>>>(x, xbf);
  prep_w<<<2048, 256, 0, stream>>>(Wih0, WihRest, Whh, bih, bhh, wih0r, wihr, whhr, biasr);
  lstm_main<<<NWG, 256, 0, stream>>>(xbf, wih0r, wihr, whhr, biasr, Wout, bout, hbuf,
                                     flags, out);
}